// Round 3
// baseline (206.100 us; speedup 1.0000x reference)
//
#include <hip/hip_runtime.h>

// x: [B=64, C=2048, J=8] fp32 ; W: [K=32, C=2048, I=16, J=8] fp32
// out v: [B=64, K=32, I=16] fp32
#define Bn 64
#define Cn 2048
#define Jn 8
#define Kn 32
#define In 16
#define EPSf 1e-7f

#define NOUT (Bn * Kn * In)          // 32768 floats per full (b,k,i) image
#define NCG  128                      // c-group copies for split-C partials

// ---------------------------------------------------------------------------
// kA: iter-1 partials. part1[cg][b][k][i] = sum_{c in cg} W[k,c,i,:].x[b,c,:]
// tid = k*8+ih, thread owns i = 2ih, 2ih+1. BSUB=8 b share each W load.
// grid = 8 bg x 128 cg = 1024 blocks; consecutive blocks same cg (L3 temporal
// locality on the W chunk). NO atomics: plain coalesced float2 stores.
// ---------------------------------------------------------------------------
#define BSUB_A 8
#define CPB_A  16
__global__ __launch_bounds__(256) void kA(const float* __restrict__ x,
                                          const float* __restrict__ W,
                                          float* __restrict__ part1)
{
    const int bg = blockIdx.x & 7;
    const int cg = blockIdx.x >> 3;
    const int k  = threadIdx.x >> 3;
    const int ih = threadIdx.x & 7;

    float acc[BSUB_A][2] = {};
    const int c0 = cg * CPB_A;

    for (int cl = 0; cl < CPB_A; ++cl) {
        const int c = c0 + cl;
        const float4* wp = (const float4*)(W + ((size_t)(k * Cn + c)) * 128 + ih * 16);
        float4 w0 = wp[0], w1 = wp[1], w2 = wp[2], w3 = wp[3];
        #pragma unroll
        for (int b = 0; b < BSUB_A; ++b) {
            const float4* xp = (const float4*)(x + ((size_t)((bg * BSUB_A + b) * Cn + c)) * 8);
            float4 x0 = xp[0], x1 = xp[1];
            acc[b][0] += w0.x*x0.x + w0.y*x0.y + w0.z*x0.z + w0.w*x0.w
                       + w1.x*x1.x + w1.y*x1.y + w1.z*x1.z + w1.w*x1.w;
            acc[b][1] += w2.x*x0.x + w2.y*x0.y + w2.z*x0.z + w2.w*x0.w
                       + w3.x*x1.x + w3.y*x1.y + w3.z*x1.z + w3.w*x1.w;
        }
    }
    float* base = part1 + (size_t)cg * NOUT;
    #pragma unroll
    for (int b = 0; b < BSUB_A; ++b) {
        float2 v = { acc[b][0], acc[b][1] };
        *(float2*)(base + ((size_t)(bg * BSUB_A + b) * Kn + k) * In + 2 * ih) = v;
    }
}

// ---------------------------------------------------------------------------
// kRed: out[o] = squash_over_i( scale * sum_cg part[cg][o] )
// 8192 threads, float4 per thread (4 consecutive i). Coalesced 16 MB read.
// i-norm via 2 xor-shuffles (4-lane groups, aligned).
// ---------------------------------------------------------------------------
__global__ __launch_bounds__(256) void kRed(const float* __restrict__ part,
                                            float* __restrict__ out,
                                            float scale)
{
    const int t = blockIdx.x * blockDim.x + threadIdx.x;   // 0..8191
    const size_t o = (size_t)t * 4;
    float4 s = make_float4(0.f, 0.f, 0.f, 0.f);
    #pragma unroll 8
    for (int cg = 0; cg < NCG; ++cg) {
        const float4 p = *(const float4*)(part + (size_t)cg * NOUT + o);
        s.x += p.x; s.y += p.y; s.z += p.z; s.w += p.w;
    }
    s.x *= scale; s.y *= scale; s.z *= scale; s.w *= scale;
    float sq = s.x*s.x + s.y*s.y + s.z*s.z + s.w*s.w;
    sq += __shfl_xor(sq, 1);
    sq += __shfl_xor(sq, 2);
    const float f = (sq / (1.0f + sq)) * rsqrtf(sq + EPSf);
    float4 r = make_float4(s.x*f, s.y*f, s.z*f, s.w*f);
    *(float4*)(out + o) = r;
}

// ---------------------------------------------------------------------------
// kC: iter-2 routing partials. tid = k*8+ih. BSUB=4 b share each W load.
// Per 8-c chunk: phase1 u->regs + exp(agreement)->LDS (3 shuffles);
// phase2 batched softmax denominators; phase3 register-only accumulate.
// grid = 16 bg x 128 cg = 2048 blocks. Plain float2 stores (no atomics).
// ---------------------------------------------------------------------------
#define BSUB_C 4
#define CCC    8
#define NCHUNK 2
__global__ __launch_bounds__(256) void kC(const float* __restrict__ x,
                                          const float* __restrict__ W,
                                          const float* __restrict__ v1,
                                          float* __restrict__ part2)
{
    const int bg = blockIdx.x & 15;
    const int cg = blockIdx.x >> 4;
    const int k  = threadIdx.x >> 3;
    const int ih = threadIdx.x & 7;

    __shared__ float e_s[BSUB_C][CCC][33];
    __shared__ float dinv[BSUB_C * CCC];

    float v1r[BSUB_C][2];
    #pragma unroll
    for (int b = 0; b < BSUB_C; ++b) {
        const float2 v = *(const float2*)(v1 + ((size_t)((bg * BSUB_C + b) * Kn + k)) * In + 2 * ih);
        v1r[b][0] = v.x;
        v1r[b][1] = v.y;
    }

    float acc[BSUB_C][2] = {};

    for (int ch = 0; ch < NCHUNK; ++ch) {
        const int c0 = cg * (NCHUNK * CCC) + ch * CCC;
        float u0[BSUB_C][CCC];
        float u1[BSUB_C][CCC];

        // ---- phase 1: u into regs, exp(agreement) into LDS ----
        #pragma unroll
        for (int cl = 0; cl < CCC; ++cl) {
            const int c = c0 + cl;
            const float4* wp = (const float4*)(W + ((size_t)(k * Cn + c)) * 128 + ih * 16);
            float4 w0 = wp[0], w1 = wp[1], w2 = wp[2], w3 = wp[3];
            #pragma unroll
            for (int b = 0; b < BSUB_C; ++b) {
                const float4* xp = (const float4*)(x + ((size_t)((bg * BSUB_C + b) * Cn + c)) * 8);
                float4 x0 = xp[0], x1 = xp[1];
                float a0 = w0.x*x0.x + w0.y*x0.y + w0.z*x0.z + w0.w*x0.w
                         + w1.x*x1.x + w1.y*x1.y + w1.z*x1.z + w1.w*x1.w;
                float a1 = w2.x*x0.x + w2.y*x0.y + w2.z*x0.z + w2.w*x0.w
                         + w3.x*x1.x + w3.y*x1.y + w3.z*x1.z + w3.w*x1.w;
                u0[b][cl] = a0;
                u1[b][cl] = a1;
                float part = a0 * v1r[b][0] + a1 * v1r[b][1];
                part += __shfl_xor(part, 1);
                part += __shfl_xor(part, 2);
                part += __shfl_xor(part, 4);
                if (ih == 0) e_s[b][cl][k] = __expf(part);
            }
        }
        __syncthreads();

        // ---- phase 2: batched softmax denominators (32 (b,c) pairs) ----
        {
            const int p  = threadIdx.x >> 3;   // 0..31
            const int l  = threadIdx.x & 7;
            const int pb = p >> 3, pc = p & 7;
            float ssum = e_s[pb][pc][4 * l + 0] + e_s[pb][pc][4 * l + 1]
                       + e_s[pb][pc][4 * l + 2] + e_s[pb][pc][4 * l + 3];
            ssum += __shfl_xor(ssum, 1);
            ssum += __shfl_xor(ssum, 2);
            ssum += __shfl_xor(ssum, 4);
            if (l == 0) dinv[p] = 1.0f / ssum;
        }
        __syncthreads();

        // ---- phase 3: weighted accumulate (register math only) ----
        #pragma unroll
        for (int cl = 0; cl < CCC; ++cl) {
            #pragma unroll
            for (int b = 0; b < BSUB_C; ++b) {
                const float cc = e_s[b][cl][k] * dinv[b * CCC + cl];
                acc[b][0] += cc * u0[b][cl];
                acc[b][1] += cc * u1[b][cl];
            }
        }
        if (ch + 1 < NCHUNK) __syncthreads();   // e_s reused next chunk
    }

    float* base = part2 + (size_t)cg * NOUT;
    #pragma unroll
    for (int b = 0; b < BSUB_C; ++b) {
        float2 v = { acc[b][0], acc[b][1] };
        *(float2*)(base + ((size_t)(bg * BSUB_C + b) * Kn + k) * In + 2 * ih) = v;
    }
}

extern "C" void kernel_launch(void* const* d_in, const int* in_sizes, int n_in,
                              void* d_out, int out_size, void* d_ws, size_t ws_size,
                              hipStream_t stream)
{
    const float* x = (const float*)d_in[0];   // [64,2048,8]
    const float* W = (const float*)d_in[1];   // [32,2048,16,8]
    float* out = (float*)d_out;               // [64,32,16]

    // ws layout: part (16 MiB, reused by kA-phase then kC-phase), then v1.
    // Stream ordering makes the alias safe: kRed1 fully consumes part before
    // kC overwrites it. No memset needed: every buffer is fully written
    // before it is read.
    float* part = (float*)d_ws;                          // NCG * NOUT floats
    float* v1   = (float*)d_ws + (size_t)NCG * NOUT;     // NOUT floats

    kA  <<<8 * NCG, 256, 0, stream>>>(x, W, part);
    kRed<<<NOUT / 4 / 256, 256, 0, stream>>>(part, v1, 1.0f / 32.0f);
    kC  <<<16 * NCG, 256, 0, stream>>>(x, W, v1, part);
    kRed<<<NOUT / 4 / 256, 256, 0, stream>>>(part, out, 1.0f);
}

// Round 4
// 195.377 us; speedup vs baseline: 1.0549x; 1.0549x over previous
//
#include <hip/hip_runtime.h>

// x: [B=64, C=2048, J=8] fp32 ; W: [K=32, C=2048, I=16, J=8] fp32
// out v: [B=64, K=32, I=16] fp32
#define Bn 64
#define Cn 2048
#define Kn 32
#define In 16
#define EPSf 1e-7f

#define NOUT (Bn * Kn * In)   // 32768 floats per (b,k,i) image
#define NCG  128              // c-group partial copies (16 c each)

__device__ __forceinline__ float dot8(float4 w0, float4 w1, float4 x0, float4 x1) {
    // balanced tree: dep depth 3 instead of an 8-deep serial chain
    return ((w0.x * x0.x + w0.y * x0.y) + (w0.z * x0.z + w0.w * x0.w))
         + ((w1.x * x1.x + w1.y * x1.y) + (w1.z * x1.z + w1.w * x1.w));
}

// ---------------------------------------------------------------------------
// kA: iter-1 partials. part1[cg][b][k][i] = sum_{c in cg} W[k,c,i,:].x[b,c,:]
// tid = k*8+ih, thread owns i = 2ih,2ih+1. BSUB=8 b share each W load.
// XCD swizzle: xcd = blk&7 owns cg band [xcd*16, xcd*16+16); bg varies
// fastest so the W chunk stays hot in that XCD's L2 across 8 bg blocks.
// 1024 blocks, ~45 VGPR, no atomics, no LDS.
// ---------------------------------------------------------------------------
#define BSUB_A 8
#define CPB_A  16
__global__ __launch_bounds__(256) void kA(const float* __restrict__ x,
                                          const float* __restrict__ W,
                                          float* __restrict__ part1)
{
    const int xcd = blockIdx.x & 7;
    const int idx = blockIdx.x >> 3;
    const int bg  = idx & 7;          // fastest: 8 bgroups share W chunk
    const int cgl = idx >> 3;         // 0..15
    const int cg  = xcd * 16 + cgl;   // 0..127
    const int k   = threadIdx.x >> 3;
    const int ih  = threadIdx.x & 7;

    float acc[BSUB_A][2] = {};
    const int c0 = cg * CPB_A;

    #pragma unroll 2
    for (int cl = 0; cl < CPB_A; ++cl) {
        const int c = c0 + cl;
        const float4* wp = (const float4*)(W + ((size_t)(k * Cn + c)) * 128 + ih * 16);
        float4 w0 = wp[0], w1 = wp[1], w2 = wp[2], w3 = wp[3];
        #pragma unroll
        for (int b = 0; b < BSUB_A; ++b) {
            const float4* xp = (const float4*)(x + ((size_t)((bg * BSUB_A + b) * Cn + c)) * 8);
            float4 x0 = xp[0], x1 = xp[1];
            acc[b][0] += dot8(w0, w1, x0, x1);
            acc[b][1] += dot8(w2, w3, x0, x1);
        }
    }
    float* base = part1 + (size_t)cg * NOUT;
    #pragma unroll
    for (int b = 0; b < BSUB_A; ++b) {
        float2 v = { acc[b][0], acc[b][1] };
        *(float2*)(base + ((size_t)(bg * BSUB_A + b) * Kn + k) * In + 2 * ih) = v;
    }
}

// ---------------------------------------------------------------------------
// kRed: out[o] = squash_over_i( scale * sum_cg part[cg][o] )
// 64 blocks x 128 threads, float4/thread. 16 MB coalesced read.
// ---------------------------------------------------------------------------
__global__ __launch_bounds__(128) void kRed(const float* __restrict__ part,
                                            float* __restrict__ out,
                                            float scale)
{
    const int t = blockIdx.x * 128 + threadIdx.x;   // 0..8191
    const size_t o = (size_t)t * 4;
    float4 s = make_float4(0.f, 0.f, 0.f, 0.f);
    #pragma unroll 4
    for (int cg = 0; cg < NCG; ++cg) {
        const float4 p = *(const float4*)(part + (size_t)cg * NOUT + o);
        s.x += p.x; s.y += p.y; s.z += p.z; s.w += p.w;
    }
    s.x *= scale; s.y *= scale; s.z *= scale; s.w *= scale;
    float sq = (s.x * s.x + s.y * s.y) + (s.z * s.z + s.w * s.w);
    sq += __shfl_xor(sq, 1);
    sq += __shfl_xor(sq, 2);
    const float f = (sq / (1.0f + sq)) * rsqrtf(sq + EPSf);
    float4 r = make_float4(s.x * f, s.y * f, s.z * f, s.w * f);
    *(float4*)(out + o) = r;
}

// ---------------------------------------------------------------------------
// kC: iter-2 routing partials, recompute structure (no u register array ->
// no AGPR spill -> high occupancy). Per 8-c chunk:
//   pass A: W loads + agreements -> exp into LDS (3 shuffles per (b,c))
//   phase 2: batched softmax denominators
//   pass B: re-load W (XCD-L2 hot), recompute u, acc += cc*u
// tid = k*8+ih. BSUB=8. Same XCD swizzle as kA. 1024 blocks.
// ---------------------------------------------------------------------------
#define BSUB_C 8
#define CCC    8
#define NCH    2
__global__ __launch_bounds__(256) void kC(const float* __restrict__ x,
                                          const float* __restrict__ W,
                                          const float* __restrict__ v1,
                                          float* __restrict__ part2)
{
    const int xcd = blockIdx.x & 7;
    const int idx = blockIdx.x >> 3;
    const int bg  = idx & 7;
    const int cgl = idx >> 3;         // 0..15
    const int cg  = xcd * 16 + cgl;   // 0..127
    const int k   = threadIdx.x >> 3;
    const int ih  = threadIdx.x & 7;

    __shared__ float e_s[BSUB_C][CCC][33];   // k padded 32->33
    __shared__ float dinv[BSUB_C * CCC];

    float v1r[BSUB_C][2];
    #pragma unroll
    for (int b = 0; b < BSUB_C; ++b) {
        const float2 v = *(const float2*)(v1 + ((size_t)((bg * BSUB_C + b) * Kn + k)) * In + 2 * ih);
        v1r[b][0] = v.x;
        v1r[b][1] = v.y;
    }

    float acc[BSUB_C][2] = {};

    for (int ch = 0; ch < NCH; ++ch) {
        const int c0 = cg * (NCH * CCC) + ch * CCC;

        // ---- pass A: agreements -> exp in LDS ----
        #pragma unroll 2
        for (int cl = 0; cl < CCC; ++cl) {
            const int c = c0 + cl;
            const float4* wp = (const float4*)(W + ((size_t)(k * Cn + c)) * 128 + ih * 16);
            float4 w0 = wp[0], w1 = wp[1], w2 = wp[2], w3 = wp[3];
            #pragma unroll
            for (int b = 0; b < BSUB_C; ++b) {
                const float4* xp = (const float4*)(x + ((size_t)((bg * BSUB_C + b) * Cn + c)) * 8);
                float4 x0 = xp[0], x1 = xp[1];
                float a0 = dot8(w0, w1, x0, x1);
                float a1 = dot8(w2, w3, x0, x1);
                float p = a0 * v1r[b][0] + a1 * v1r[b][1];
                p += __shfl_xor(p, 1);
                p += __shfl_xor(p, 2);
                p += __shfl_xor(p, 4);
                if (ih == 0) e_s[b][cl][k] = __expf(p);
            }
        }
        __syncthreads();

        // ---- phase 2: softmax denominators for 64 (b,c) pairs ----
        {
            const int p  = threadIdx.x >> 2;   // 0..63
            const int l  = threadIdx.x & 3;
            const int pb = p >> 3, pc = p & 7;
            const float* ep = &e_s[pb][pc][8 * l];
            float ssum = ((ep[0] + ep[1]) + (ep[2] + ep[3]))
                       + ((ep[4] + ep[5]) + (ep[6] + ep[7]));
            ssum += __shfl_xor(ssum, 1);
            ssum += __shfl_xor(ssum, 2);
            if (l == 0) dinv[p] = 1.0f / ssum;
        }
        __syncthreads();

        // ---- pass B: recompute u from L2-hot W, weighted accumulate ----
        #pragma unroll 2
        for (int cl = 0; cl < CCC; ++cl) {
            const int c = c0 + cl;
            const float4* wp = (const float4*)(W + ((size_t)(k * Cn + c)) * 128 + ih * 16);
            float4 w0 = wp[0], w1 = wp[1], w2 = wp[2], w3 = wp[3];
            #pragma unroll
            for (int b = 0; b < BSUB_C; ++b) {
                const float4* xp = (const float4*)(x + ((size_t)((bg * BSUB_C + b) * Cn + c)) * 8);
                float4 x0 = xp[0], x1 = xp[1];
                float a0 = dot8(w0, w1, x0, x1);
                float a1 = dot8(w2, w3, x0, x1);
                const float cc = e_s[b][cl][k] * dinv[b * CCC + cl];
                acc[b][0] += cc * a0;
                acc[b][1] += cc * a1;
            }
        }
        if (ch + 1 < NCH) __syncthreads();   // e_s reused next chunk
    }

    float* base = part2 + (size_t)cg * NOUT;
    #pragma unroll
    for (int b = 0; b < BSUB_C; ++b) {
        float2 v = { acc[b][0], acc[b][1] };
        *(float2*)(base + ((size_t)(bg * BSUB_C + b) * Kn + k) * In + 2 * ih) = v;
    }
}

extern "C" void kernel_launch(void* const* d_in, const int* in_sizes, int n_in,
                              void* d_out, int out_size, void* d_ws, size_t ws_size,
                              hipStream_t stream)
{
    const float* x = (const float*)d_in[0];   // [64,2048,8]
    const float* W = (const float*)d_in[1];   // [32,2048,16,8]
    float* out = (float*)d_out;               // [64,32,16]

    // ws: part (16 MiB, reused by iter-1 then iter-2 partials; kRed1 fully
    // consumes it before kC overwrites — stream-ordered), then v1.
    float* part = (float*)d_ws;                       // NCG * NOUT floats
    float* v1   = (float*)d_ws + (size_t)NCG * NOUT;  // NOUT floats

    kA  <<<1024, 256, 0, stream>>>(x, W, part);
    kRed<<<64, 128, 0, stream>>>(part, v1, 1.0f / 32.0f);
    kC  <<<1024, 256, 0, stream>>>(x, W, v1, part);
    kRed<<<64, 128, 0, stream>>>(part, out, 1.0f);
}

// Round 5
// 177.975 us; speedup vs baseline: 1.1580x; 1.0978x over previous
//
#include <hip/hip_runtime.h>

// x: [B=64, C=2048, J=8] fp32 ; W: [K=32, C=2048, I=16, J=8] fp32
// out v: [B=64, K=32, I=16] fp32
#define Bn 64
#define Cn 2048
#define Kn 32
#define In 16
#define EPSf 1e-7f

#define NOUT (Bn * Kn * In)   // 32768
#define NCG  128              // iter-2 c-group partials
#define KJ   (Cn * 8)         // 16384 = contraction length (c,j)
#define KSPLIT 32             // GEMM K-splits (16 ksteps of 32 each)

typedef short bf8v __attribute__((ext_vector_type(8)));   // 8 bf16 in 4 VGPRs
typedef float f4v  __attribute__((ext_vector_type(4)));

union U16B { uint4 u; bf8v v; unsigned short h[8]; };

__device__ __forceinline__ unsigned short f2bf(float f) {
    unsigned u = __float_as_uint(f);
    u += 0x7FFF + ((u >> 16) & 1);          // round-to-nearest-even
    return (unsigned short)(u >> 16);
}

__device__ __forceinline__ float dot8(float4 w0, float4 w1, float4 x0, float4 x1) {
    return ((w0.x * x0.x + w0.y * x0.y) + (w0.z * x0.z + w0.w * x0.w))
         + ((w1.x * x1.x + w1.y * x1.y) + (w1.z * x1.z + w1.w * x1.w));
}

// ---------------------------------------------------------------------------
// kPrepX: x fp32 -> xb bf16, natural [b][cj] layout (pure convert).
// 131072 threads, 8 elems each: float4x2 read, uint4 write. ~1 us.
// ---------------------------------------------------------------------------
__global__ __launch_bounds__(256) void kPrepX(const float* __restrict__ x,
                                              unsigned short* __restrict__ xb)
{
    const int g = blockIdx.x * 256 + threadIdx.x;        // 0..131071
    const float4* s = (const float4*)(x + (size_t)g * 8);
    float4 a = s[0], b = s[1];
    U16B o;
    o.h[0] = f2bf(a.x); o.h[1] = f2bf(a.y); o.h[2] = f2bf(a.z); o.h[3] = f2bf(a.w);
    o.h[4] = f2bf(b.x); o.h[5] = f2bf(b.y); o.h[6] = f2bf(b.z); o.h[7] = f2bf(b.w);
    ((uint4*)xb)[g] = o.u;
}

// ---------------------------------------------------------------------------
// kPrepW: W fp32 -> bf16 B-fragments in EXACT mfma_16x16x32 B-operand order:
// wt[ntile][kstep][lane][8] with  n = ntile*16 + (lane&15) = (k_out,i),
// cj = kstep*32 + (lane>>4)*8 + t.  j (=t) is contiguous in W -> each thread
// reads 32 B contiguous; a wave reads 2 KB contiguous; writes 1 KB coalesced.
// 1048576 threads. ~8 us (50 MB moved).
// ---------------------------------------------------------------------------
__global__ __launch_bounds__(256) void kPrepW(const float* __restrict__ W,
                                              unsigned short* __restrict__ wt)
{
    const int g     = blockIdx.x * 256 + threadIdx.x;    // 0..1048575
    const int lane  = g & 63;
    const int kstep = (g >> 6) & 511;
    const int ntile = g >> 15;                            // 0..31
    const int n  = ntile * 16 + (lane & 15);
    const int ko = n >> 4;
    const int i  = n & 15;
    const int c  = (kstep * 32 + (lane >> 4) * 8) >> 3;
    const float4* s = (const float4*)(W + (((size_t)ko * Cn + c) * 16 + i) * 8);
    float4 a = s[0], b = s[1];
    U16B o;
    o.h[0] = f2bf(a.x); o.h[1] = f2bf(a.y); o.h[2] = f2bf(a.z); o.h[3] = f2bf(a.w);
    o.h[4] = f2bf(b.x); o.h[5] = f2bf(b.y); o.h[6] = f2bf(b.z); o.h[7] = f2bf(b.w);
    ((uint4*)wt)[g] = o.u;
}

// ---------------------------------------------------------------------------
// kGemm1: S1 partials via MFMA.  D[b, n=(k,i)] = sum_cj x[b,cj] * Wt[cj,n].
// 256 blocks = 8 nstrips x 32 ksplits; 4 waves/block = 4 m-tiles (all of B).
// Each wave: 4 acc tiles (16x64 n-strip), 16 ksteps x 4 MFMA, dep-distance 4.
// A-frag: lane&15 = m row, (lane>>4)*8 = k offset (natural xb layout).
// B-frag: direct coalesced load of pre-swizzled wt.  ~45 VGPR.
// ---------------------------------------------------------------------------
__global__ __launch_bounds__(256) void kGemm1(const unsigned short* __restrict__ xb,
                                              const unsigned short* __restrict__ wt,
                                              float* __restrict__ part1)
{
    const int nstrip = blockIdx.x & 7;
    const int ksplit = blockIdx.x >> 3;       // 0..31
    const int ks0    = ksplit * (512 / KSPLIT);
    const int lane   = threadIdx.x & 63;
    const int m0     = (threadIdx.x >> 6) * 16;

    f4v acc[4] = {};
    const unsigned short* arow = xb + (size_t)(m0 + (lane & 15)) * KJ + (lane >> 4) * 8;

    for (int s = 0; s < 512 / KSPLIT; ++s) {
        const int ks = ks0 + s;
        U16B af;
        af.u = *(const uint4*)(arow + ks * 32);
        #pragma unroll
        for (int t = 0; t < 4; ++t) {
            const int nt = nstrip * 4 + t;
            U16B bf;
            bf.u = *(const uint4*)(wt + (((size_t)nt * 512 + ks) * 64 + lane) * 8);
            acc[t] = __builtin_amdgcn_mfma_f32_16x16x32_bf16(af.v, bf.v, acc[t], 0, 0, 0);
        }
    }

    // C/D layout: col = lane&15, row = (lane>>4)*4 + reg  (verified m89/m91)
    float* pb = part1 + (size_t)ksplit * NOUT;
    const int col   = lane & 15;
    const int rbase = (lane >> 4) * 4;
    #pragma unroll
    for (int t = 0; t < 4; ++t) {
        const int n = (nstrip * 4 + t) * 16 + col;
        #pragma unroll
        for (int r = 0; r < 4; ++r)
            pb[(size_t)(m0 + rbase + r) * 512 + n] = acc[t][r];
    }
}

// ---------------------------------------------------------------------------
// kSq1: v1 = squash( (1/32) * sum_splits part1 ).  8192 threads, float4 each.
// ---------------------------------------------------------------------------
__global__ __launch_bounds__(256) void kSq1(const float* __restrict__ part1,
                                            float* __restrict__ v1)
{
    const int t = blockIdx.x * 256 + threadIdx.x;   // 0..8191
    const size_t o = (size_t)t * 4;
    float4 s = make_float4(0.f, 0.f, 0.f, 0.f);
    #pragma unroll 8
    for (int g = 0; g < KSPLIT; ++g) {
        const float4 p = *(const float4*)(part1 + (size_t)g * NOUT + o);
        s.x += p.x; s.y += p.y; s.z += p.z; s.w += p.w;
    }
    const float sc = 1.0f / 32.0f;
    s.x *= sc; s.y *= sc; s.z *= sc; s.w *= sc;
    float sq = (s.x * s.x + s.y * s.y) + (s.z * s.z + s.w * s.w);
    sq += __shfl_xor(sq, 1);
    sq += __shfl_xor(sq, 2);
    const float f = (sq / (1.0f + sq)) * rsqrtf(sq + EPSf);
    *(float4*)(v1 + o) = make_float4(s.x * f, s.y * f, s.z * f, s.w * f);
}

// ---------------------------------------------------------------------------
// kC: iter-2 routing partials (UNCHANGED from R4 — control).
// ---------------------------------------------------------------------------
#define BSUB_C 8
#define CCC    8
#define NCH    2
__global__ __launch_bounds__(256) void kC(const float* __restrict__ x,
                                          const float* __restrict__ W,
                                          const float* __restrict__ v1,
                                          float* __restrict__ part2)
{
    const int xcd = blockIdx.x & 7;
    const int idx = blockIdx.x >> 3;
    const int bg  = idx & 7;
    const int cgl = idx >> 3;
    const int cg  = xcd * 16 + cgl;
    const int k   = threadIdx.x >> 3;
    const int ih  = threadIdx.x & 7;

    __shared__ float e_s[BSUB_C][CCC][33];
    __shared__ float dinv[BSUB_C * CCC];

    float v1r[BSUB_C][2];
    #pragma unroll
    for (int b = 0; b < BSUB_C; ++b) {
        const float2 v = *(const float2*)(v1 + ((size_t)((bg * BSUB_C + b) * Kn + k)) * In + 2 * ih);
        v1r[b][0] = v.x;
        v1r[b][1] = v.y;
    }

    float acc[BSUB_C][2] = {};

    for (int ch = 0; ch < NCH; ++ch) {
        const int c0 = cg * (NCH * CCC) + ch * CCC;

        #pragma unroll 2
        for (int cl = 0; cl < CCC; ++cl) {
            const int c = c0 + cl;
            const float4* wp = (const float4*)(W + ((size_t)(k * Cn + c)) * 128 + ih * 16);
            float4 w0 = wp[0], w1 = wp[1], w2 = wp[2], w3 = wp[3];
            #pragma unroll
            for (int b = 0; b < BSUB_C; ++b) {
                const float4* xp = (const float4*)(x + ((size_t)((bg * BSUB_C + b) * Cn + c)) * 8);
                float4 x0 = xp[0], x1 = xp[1];
                float a0 = dot8(w0, w1, x0, x1);
                float a1 = dot8(w2, w3, x0, x1);
                float p = a0 * v1r[b][0] + a1 * v1r[b][1];
                p += __shfl_xor(p, 1);
                p += __shfl_xor(p, 2);
                p += __shfl_xor(p, 4);
                if (ih == 0) e_s[b][cl][k] = __expf(p);
            }
        }
        __syncthreads();

        {
            const int p  = threadIdx.x >> 2;
            const int l  = threadIdx.x & 3;
            const int pb = p >> 3, pc = p & 7;
            const float* ep = &e_s[pb][pc][8 * l];
            float ssum = ((ep[0] + ep[1]) + (ep[2] + ep[3]))
                       + ((ep[4] + ep[5]) + (ep[6] + ep[7]));
            ssum += __shfl_xor(ssum, 1);
            ssum += __shfl_xor(ssum, 2);
            if (l == 0) dinv[p] = 1.0f / ssum;
        }
        __syncthreads();

        #pragma unroll 2
        for (int cl = 0; cl < CCC; ++cl) {
            const int c = c0 + cl;
            const float4* wp = (const float4*)(W + ((size_t)(k * Cn + c)) * 128 + ih * 16);
            float4 w0 = wp[0], w1 = wp[1], w2 = wp[2], w3 = wp[3];
            #pragma unroll
            for (int b = 0; b < BSUB_C; ++b) {
                const float4* xp = (const float4*)(x + ((size_t)((bg * BSUB_C + b) * Cn + c)) * 8);
                float4 x0 = xp[0], x1 = xp[1];
                float a0 = dot8(w0, w1, x0, x1);
                float a1 = dot8(w2, w3, x0, x1);
                const float cc = e_s[b][cl][k] * dinv[b * CCC + cl];
                acc[b][0] += cc * a0;
                acc[b][1] += cc * a1;
            }
        }
        if (ch + 1 < NCH) __syncthreads();
    }

    float* base = part2 + (size_t)cg * NOUT;
    #pragma unroll
    for (int b = 0; b < BSUB_C; ++b) {
        float2 v = { acc[b][0], acc[b][1] };
        *(float2*)(base + ((size_t)(bg * BSUB_C + b) * Kn + k) * In + 2 * ih) = v;
    }
}

// ---------------------------------------------------------------------------
// kRed2: out = squash( sum_cg part2 ).  16384 threads, float2 each (2x the
// parallelism of the old kRed), 128-deep load stream per thread.
// ---------------------------------------------------------------------------
__global__ __launch_bounds__(256) void kRed2(const float* __restrict__ part,
                                             float* __restrict__ out)
{
    const int t = blockIdx.x * 256 + threadIdx.x;   // 0..16383
    const size_t o = (size_t)t * 2;
    float2 s = make_float2(0.f, 0.f);
    #pragma unroll 8
    for (int cg = 0; cg < NCG; ++cg) {
        const float2 p = *(const float2*)(part + (size_t)cg * NOUT + o);
        s.x += p.x; s.y += p.y;
    }
    float sq = s.x * s.x + s.y * s.y;
    sq += __shfl_xor(sq, 1);
    sq += __shfl_xor(sq, 2);
    sq += __shfl_xor(sq, 4);
    const float f = (sq / (1.0f + sq)) * rsqrtf(sq + EPSf);
    *(float2*)(out + o) = make_float2(s.x * f, s.y * f);
}

extern "C" void kernel_launch(void* const* d_in, const int* in_sizes, int n_in,
                              void* d_out, int out_size, void* d_ws, size_t ws_size,
                              hipStream_t stream)
{
    const float* x = (const float*)d_in[0];   // [64,2048,8]
    const float* W = (const float*)d_in[1];   // [32,2048,16,8]
    float* out = (float*)d_out;               // [64,32,16]

    // ws layout (floats). part2 ALIASES wt: wt is dead after kGemm1, part2 is
    // written by kC afterwards — stream-ordered, safe.
    float* wsf = (float*)d_ws;
    unsigned short* wt   = (unsigned short*)(wsf);                    // 16 MiB frag-order bf16 W
    float*          part2 = wsf;                                      // 16 MiB (alias)
    unsigned short* xb   = (unsigned short*)(wsf + 4194304);          // 2 MiB bf16 x
    float*          part1 = wsf + 4194304 + 524288;                   // 4 MiB GEMM partials
    float*          v1    = wsf + 4194304 + 524288 + 1048576;         // 128 KiB

    kPrepX<<<512,  256, 0, stream>>>(x, xb);
    kPrepW<<<4096, 256, 0, stream>>>(W, wt);
    kGemm1<<<256,  256, 0, stream>>>(xb, wt, part1);
    kSq1  <<<32,   256, 0, stream>>>(part1, v1);
    kC    <<<1024, 256, 0, stream>>>(x, W, v1, part2);
    kRed2 <<<64,   256, 0, stream>>>(part2, out);
}